// Round 1
// baseline (1071.127 us; speedup 1.0000x reference)
//
#include <hip/hip_runtime.h>
#include <hip/hip_bf16.h>

#define B_ 4096
#define I_ 1024
#define H_ 2048
#define O_ 1024

typedef short v8s __attribute__((ext_vector_type(8)));
typedef float v4f __attribute__((ext_vector_type(4)));

__device__ __forceinline__ ushort f2bf(float f) {
    unsigned u = __float_as_uint(f);
    u += 0x7fffu + ((u >> 16) & 1u);   // round-to-nearest-even
    return (ushort)(u >> 16);
}
__device__ __forceinline__ float sigm(float x) { return 1.f / (1.f + __expf(-x)); }
__device__ __forceinline__ float tanh_f(float x) {
    x = fminf(15.f, fmaxf(-15.f, x));
    float e = __expf(2.f * x);
    return (e - 1.f) / (e + 1.f);
}

#define LDSTRIDE 48   // 128x32 bf16 tile, padded row stride (96B = 6x16B, kills 8-way conflicts)

// GEMM1: gates[m][n] = sum_k [x|h][m][k] * Wcat[n][k] + b[n]; n = 4*h + gate (interleaved)
// Fused epilogue: sigmoid/tanh gate math -> new_cell, new_hidden
__global__ __launch_bounds__(256) void lstm_gates_gemm(
    const float* __restrict__ x, const float* __restrict__ hs, const float* __restrict__ cs,
    const float* __restrict__ Wxi, const float* __restrict__ bxi, const float* __restrict__ Whi,
    const float* __restrict__ Wxf, const float* __restrict__ bxf, const float* __restrict__ Whf,
    const float* __restrict__ Wxc, const float* __restrict__ bxc, const float* __restrict__ Whc,
    const float* __restrict__ Wxo, const float* __restrict__ bxo, const float* __restrict__ Who,
    float* __restrict__ hid_out, float* __restrict__ cell_out)
{
    __shared__ ushort As[128 * LDSTRIDE];
    __shared__ ushort Bs[128 * LDSTRIDE];
    const int tid  = threadIdx.x;
    const int lane = tid & 63;
    const int wid  = tid >> 6;
    const int wm = wid >> 1, wn = wid & 1;
    const int blkN = blockIdx.x, blkM = blockIdx.y;

    const int r_s = tid >> 3;        // 0..31
    const int c_s = (tid & 7) * 4;   // 0..28

    v4f acc[4][4];
    #pragma unroll
    for (int i = 0; i < 4; ++i)
      #pragma unroll
      for (int j = 0; j < 4; ++j) acc[i][j] = (v4f)0.f;

    for (int k0 = 0; k0 < I_ + H_; k0 += 32) {
        const bool seg0 = (k0 < I_);
        #pragma unroll
        for (int it = 0; it < 4; ++it) {
            const int row = it * 32 + r_s;
            // ---- A tile: virtual [x | h] row-major, K contiguous
            const int gm = blkM * 128 + row;
            const float* srcA = seg0 ? (x  + (size_t)gm * I_ + (k0 + c_s))
                                     : (hs + (size_t)gm * H_ + (k0 - I_ + c_s));
            float4 va = *(const float4*)srcA;
            *(ushort4*)&As[row * LDSTRIDE + c_s] =
                make_ushort4(f2bf(va.x), f2bf(va.y), f2bf(va.z), f2bf(va.w));
            // ---- B tile: Wcat[n][k], n = 4*h + g
            const int n = blkN * 128 + row;
            const int hh = n >> 2, g = n & 3;
            const float* Wp;
            if (seg0) {
                const float* W = (g == 0) ? Wxi : (g == 1) ? Wxf : (g == 2) ? Wxc : Wxo;
                Wp = W + (size_t)hh * I_ + (k0 + c_s);
            } else {
                const float* W = (g == 0) ? Whi : (g == 1) ? Whf : (g == 2) ? Whc : Who;
                Wp = W + (size_t)hh * H_ + (k0 - I_ + c_s);
            }
            float4 vb = *(const float4*)Wp;
            *(ushort4*)&Bs[row * LDSTRIDE + c_s] =
                make_ushort4(f2bf(vb.x), f2bf(vb.y), f2bf(vb.z), f2bf(vb.w));
        }
        __syncthreads();
        v8s afr[4], bfr[4];
        #pragma unroll
        for (int i = 0; i < 4; ++i)
            afr[i] = *(const v8s*)&As[(wm * 64 + i * 16 + (lane & 15)) * LDSTRIDE + (lane >> 4) * 8];
        #pragma unroll
        for (int j = 0; j < 4; ++j)
            bfr[j] = *(const v8s*)&Bs[(wn * 64 + j * 16 + (lane & 15)) * LDSTRIDE + (lane >> 4) * 8];
        #pragma unroll
        for (int i = 0; i < 4; ++i)
          #pragma unroll
          for (int j = 0; j < 4; ++j)
            acc[i][j] = __builtin_amdgcn_mfma_f32_16x16x32_bf16(afr[i], bfr[j], acc[i][j], 0, 0, 0);
        __syncthreads();
    }

    // ---- fused LSTM epilogue. gate g = lane&3 within each quad; h = n>>2 shared by quad.
    const int g = lane & 3;
    int hj[4]; float biasj[4];
    #pragma unroll
    for (int j = 0; j < 4; ++j) {
        const int n = blkN * 128 + wn * 64 + j * 16 + (lane & 15);
        hj[j] = n >> 2;
        const float* bp = (g == 0) ? bxi : (g == 1) ? bxf : (g == 2) ? bxc : bxo;
        biasj[j] = bp[hj[j]];
    }
    #pragma unroll
    for (int i = 0; i < 4; ++i) {
      #pragma unroll
      for (int r = 0; r < 4; ++r) {
        const int m = blkM * 128 + wm * 64 + i * 16 + (lane >> 4) * 4 + r;
        #pragma unroll
        for (int j = 0; j < 4; ++j) {
            const float v = acc[i][j][r] + biasj[j];
            const int q = lane & 60;
            const float gi = __shfl(v, q + 0, 64);
            const float gf = __shfl(v, q + 1, 64);
            const float gc = __shfl(v, q + 2, 64);
            const float go = __shfl(v, q + 3, 64);
            const float Ig = sigm(gi), Fg = sigm(gf);
            const float Cg = tanh_f(gc), Og = sigm(go);
            const int h = hj[j];
            const float c_old = cs[(size_t)m * H_ + h];
            const float c_new = Fg * c_old + Ig * Cg;
            const float h_new = Og * tanh_f(c_new);
            if (g == 0)      cell_out[(size_t)m * H_ + h] = c_new;
            else if (g == 1) hid_out [(size_t)m * H_ + h] = h_new;
        }
      }
    }
}

// GEMM2: out[m][n] = sum_k hid[m][k] * Why[n][k] + b[n]
__global__ __launch_bounds__(256) void out_gemm(
    const float* __restrict__ hid, const float* __restrict__ Why,
    const float* __restrict__ bw, float* __restrict__ out)
{
    __shared__ ushort As[128 * LDSTRIDE];
    __shared__ ushort Bs[128 * LDSTRIDE];
    const int tid  = threadIdx.x;
    const int lane = tid & 63;
    const int wid  = tid >> 6;
    const int wm = wid >> 1, wn = wid & 1;
    const int blkN = blockIdx.x, blkM = blockIdx.y;
    const int r_s = tid >> 3;
    const int c_s = (tid & 7) * 4;

    v4f acc[4][4];
    #pragma unroll
    for (int i = 0; i < 4; ++i)
      #pragma unroll
      for (int j = 0; j < 4; ++j) acc[i][j] = (v4f)0.f;

    for (int k0 = 0; k0 < H_; k0 += 32) {
        #pragma unroll
        for (int it = 0; it < 4; ++it) {
            const int row = it * 32 + r_s;
            const int gm = blkM * 128 + row;
            float4 va = *(const float4*)(hid + (size_t)gm * H_ + (k0 + c_s));
            *(ushort4*)&As[row * LDSTRIDE + c_s] =
                make_ushort4(f2bf(va.x), f2bf(va.y), f2bf(va.z), f2bf(va.w));
            const int n = blkN * 128 + row;
            float4 vb = *(const float4*)(Why + (size_t)n * H_ + (k0 + c_s));
            *(ushort4*)&Bs[row * LDSTRIDE + c_s] =
                make_ushort4(f2bf(vb.x), f2bf(vb.y), f2bf(vb.z), f2bf(vb.w));
        }
        __syncthreads();
        v8s afr[4], bfr[4];
        #pragma unroll
        for (int i = 0; i < 4; ++i)
            afr[i] = *(const v8s*)&As[(wm * 64 + i * 16 + (lane & 15)) * LDSTRIDE + (lane >> 4) * 8];
        #pragma unroll
        for (int j = 0; j < 4; ++j)
            bfr[j] = *(const v8s*)&Bs[(wn * 64 + j * 16 + (lane & 15)) * LDSTRIDE + (lane >> 4) * 8];
        #pragma unroll
        for (int i = 0; i < 4; ++i)
          #pragma unroll
          for (int j = 0; j < 4; ++j)
            acc[i][j] = __builtin_amdgcn_mfma_f32_16x16x32_bf16(afr[i], bfr[j], acc[i][j], 0, 0, 0);
        __syncthreads();
    }
    #pragma unroll
    for (int i = 0; i < 4; ++i) {
      #pragma unroll
      for (int r = 0; r < 4; ++r) {
        const int m = blkM * 128 + wm * 64 + i * 16 + (lane >> 4) * 4 + r;
        #pragma unroll
        for (int j = 0; j < 4; ++j) {
            const int n = blkN * 128 + wn * 64 + j * 16 + (lane & 15);
            out[(size_t)m * O_ + n] = acc[i][j][r] + bw[n];
        }
      }
    }
}

extern "C" void kernel_launch(void* const* d_in, const int* in_sizes, int n_in,
                              void* d_out, int out_size, void* d_ws, size_t ws_size,
                              hipStream_t stream) {
    const float* x   = (const float*)d_in[0];
    const float* hs  = (const float*)d_in[1];
    const float* cs  = (const float*)d_in[2];
    const float* Wxi = (const float*)d_in[3];
    const float* bxi = (const float*)d_in[4];
    const float* Whi = (const float*)d_in[5];
    const float* Wxf = (const float*)d_in[6];
    const float* bxf = (const float*)d_in[7];
    const float* Whf = (const float*)d_in[8];
    const float* Wxc = (const float*)d_in[9];
    const float* bxc = (const float*)d_in[10];
    const float* Whc = (const float*)d_in[11];
    const float* Wxo = (const float*)d_in[12];
    const float* bxo = (const float*)d_in[13];
    const float* Who = (const float*)d_in[14];
    const float* Why = (const float*)d_in[15];
    const float* bwy = (const float*)d_in[16];

    float* out      = (float*)d_out;
    float* hid_out  = out + (size_t)B_ * O_;
    float* cell_out = hid_out + (size_t)B_ * H_;

    lstm_gates_gemm<<<dim3(64, 32), 256, 0, stream>>>(
        x, hs, cs, Wxi, bxi, Whi, Wxf, bxf, Whf, Wxc, bxc, Whc, Wxo, bxo, Who,
        hid_out, cell_out);
    out_gemm<<<dim3(8, 32), 256, 0, stream>>>(hid_out, Why, bwy, out);
}

// Round 2
// 454.513 us; speedup vs baseline: 2.3566x; 2.3566x over previous
//
#include <hip/hip_runtime.h>
#include <hip/hip_bf16.h>

#define B_ 4096
#define I_ 1024
#define H_ 2048
#define O_ 1024
#define K1 (I_ + H_)   // 3072
#define N1 (4 * H_)    // 8192

typedef short v8s __attribute__((ext_vector_type(8)));
typedef float v4f __attribute__((ext_vector_type(4)));

__device__ __forceinline__ ushort f2bf(float f) {
    unsigned u = __float_as_uint(f);
    u += 0x7fffu + ((u >> 16) & 1u);   // RNE
    return (ushort)(u >> 16);
}
__device__ __forceinline__ float sigm(float x) { return 1.f / (1.f + __expf(-x)); }
__device__ __forceinline__ float tanh_f(float x) {
    x = fminf(15.f, fmaxf(-15.f, x));
    float e = __expf(2.f * x);
    return (e - 1.f) / (e + 1.f);
}
__device__ __forceinline__ void gload16(const void* g, void* l) {
    __builtin_amdgcn_global_load_lds(
        (const __attribute__((address_space(1))) void*)g,
        (__attribute__((address_space(3))) void*)l, 16, 0, 0);
}

// ---------------------------------------------------------------- conversion
// Wcat[n][k], n = 4*h+g, k = [x-part 1024 | h-part 2048]
__global__ __launch_bounds__(384) void convert_w(
    const float* __restrict__ Wxi, const float* __restrict__ Whi,
    const float* __restrict__ Wxf, const float* __restrict__ Whf,
    const float* __restrict__ Wxc, const float* __restrict__ Whc,
    const float* __restrict__ Wxo, const float* __restrict__ Who,
    ushort* __restrict__ Wcat)
{
    const int n = blockIdx.x;          // 0..8191
    const int k = threadIdx.x * 8;     // 0..3064
    const int h = n >> 2, g = n & 3;
    const float* src;
    if (k < I_) {
        const float* W = (g == 0) ? Wxi : (g == 1) ? Wxf : (g == 2) ? Wxc : Wxo;
        src = W + (size_t)h * I_ + k;
    } else {
        const float* W = (g == 0) ? Whi : (g == 1) ? Whf : (g == 2) ? Whc : Who;
        src = W + (size_t)h * H_ + (k - I_);
    }
    float4 a = *(const float4*)src;
    float4 b = *(const float4*)(src + 4);
    ushort4 lo = make_ushort4(f2bf(a.x), f2bf(a.y), f2bf(a.z), f2bf(a.w));
    ushort4 hi = make_ushort4(f2bf(b.x), f2bf(b.y), f2bf(b.z), f2bf(b.w));
    *(ushort4*)&Wcat[(size_t)n * K1 + k] = lo;
    *(ushort4*)&Wcat[(size_t)n * K1 + k + 4] = hi;
}

// Xcat[m][k] = [x | h] bf16
__global__ __launch_bounds__(384) void convert_x(
    const float* __restrict__ x, const float* __restrict__ hs, ushort* __restrict__ Xcat)
{
    const int m = blockIdx.x;          // 0..4095
    const int k = threadIdx.x * 8;
    const float* src = (k < I_) ? (x + (size_t)m * I_ + k)
                                : (hs + (size_t)m * H_ + (k - I_));
    float4 a = *(const float4*)src;
    float4 b = *(const float4*)(src + 4);
    *(ushort4*)&Xcat[(size_t)m * K1 + k] =
        make_ushort4(f2bf(a.x), f2bf(a.y), f2bf(a.z), f2bf(a.w));
    *(ushort4*)&Xcat[(size_t)m * K1 + k + 4] =
        make_ushort4(f2bf(b.x), f2bf(b.y), f2bf(b.z), f2bf(b.w));
}

__global__ __launch_bounds__(256) void convert_y(
    const float* __restrict__ Why, ushort* __restrict__ WhyB)
{
    const int n = blockIdx.x;          // 0..1023
    const int k = threadIdx.x * 8;     // 0..2040
    const float* src = Why + (size_t)n * H_ + k;
    float4 a = *(const float4*)src;
    float4 b = *(const float4*)(src + 4);
    *(ushort4*)&WhyB[(size_t)n * H_ + k] =
        make_ushort4(f2bf(a.x), f2bf(a.y), f2bf(a.z), f2bf(a.w));
    *(ushort4*)&WhyB[(size_t)n * H_ + k + 4] =
        make_ushort4(f2bf(b.x), f2bf(b.y), f2bf(b.z), f2bf(b.w));
}

// ------------------------------------------------------- fast bf16 GEMM cores
// m97 structure: 128x128 tile, BK=32, 4 waves (2x2), global_load_lds width 16,
// linear LDS [128][32] bf16.

// GEMM1: gates = Xcat @ Wcat^T, fused LSTM gate epilogue.
__global__ __launch_bounds__(256) void gates_mm_bf16(
    const ushort* __restrict__ A, const ushort* __restrict__ Bm,
    const float* __restrict__ cs,
    const float* __restrict__ bxi, const float* __restrict__ bxf,
    const float* __restrict__ bxc, const float* __restrict__ bxo,
    float* __restrict__ hid_out, float* __restrict__ cell_out,
    ushort* __restrict__ hidB)
{
    __shared__ ushort As[128 * 32];
    __shared__ ushort Bs[128 * 32];
    const int tid  = threadIdx.x;
    const int lane = tid & 63;
    const int w    = tid >> 6;
    const int wm = w >> 1, wn = w & 1;
    const int blkN = blockIdx.x, blkM = blockIdx.y;

    const int srow = w * 16 + (lane >> 2);   // staging row within 64-row half
    const int scol = (lane & 3) * 8;         // staging col (bf16 elems)

    v4f acc[4][4];
    #pragma unroll
    for (int i = 0; i < 4; ++i)
      #pragma unroll
      for (int j = 0; j < 4; ++j) acc[i][j] = (v4f)0.f;

    for (int k0 = 0; k0 < K1; k0 += 32) {
        #pragma unroll
        for (int it = 0; it < 2; ++it) {
            const int row = it * 64 + srow;
            gload16(A  + (size_t)(blkM * 128 + row) * K1 + k0 + scol,
                    &As[w * 512 + it * 2048]);
            gload16(Bm + (size_t)(blkN * 128 + row) * K1 + k0 + scol,
                    &Bs[w * 512 + it * 2048]);
        }
        __syncthreads();
        v8s afr[4], bfr[4];
        #pragma unroll
        for (int i = 0; i < 4; ++i)
            afr[i] = *(const v8s*)&As[(wm * 64 + i * 16 + (lane & 15)) * 32 + (lane >> 4) * 8];
        #pragma unroll
        for (int j = 0; j < 4; ++j)
            bfr[j] = *(const v8s*)&Bs[(wn * 64 + j * 16 + (lane & 15)) * 32 + (lane >> 4) * 8];
        #pragma unroll
        for (int i = 0; i < 4; ++i)
          #pragma unroll
          for (int j = 0; j < 4; ++j)
            acc[i][j] = __builtin_amdgcn_mfma_f32_16x16x32_bf16(afr[i], bfr[j], acc[i][j], 0, 0, 0);
        __syncthreads();
    }

    // fused LSTM epilogue: quad lanes hold gates i,f,c,o of one hidden unit
    const int g = lane & 3;
    int hj[4]; float biasj[4];
    #pragma unroll
    for (int j = 0; j < 4; ++j) {
        const int n = blkN * 128 + wn * 64 + j * 16 + (lane & 15);
        hj[j] = n >> 2;
        const float* bp = (g == 0) ? bxi : (g == 1) ? bxf : (g == 2) ? bxc : bxo;
        biasj[j] = bp[hj[j]];
    }
    #pragma unroll
    for (int i = 0; i < 4; ++i) {
      #pragma unroll
      for (int r = 0; r < 4; ++r) {
        const int m = blkM * 128 + wm * 64 + i * 16 + (lane >> 4) * 4 + r;
        #pragma unroll
        for (int j = 0; j < 4; ++j) {
            const float v = acc[i][j][r] + biasj[j];
            const int q = lane & 60;
            const float gi = __shfl(v, q + 0, 64);
            const float gf = __shfl(v, q + 1, 64);
            const float gc = __shfl(v, q + 2, 64);
            const float go = __shfl(v, q + 3, 64);
            const float Ig = sigm(gi), Fg = sigm(gf);
            const float Cg = tanh_f(gc), Og = sigm(go);
            const int h = hj[j];
            const float c_old = cs[(size_t)m * H_ + h];
            const float c_new = Fg * c_old + Ig * Cg;
            const float h_new = Og * tanh_f(c_new);
            if (g == 0)      cell_out[(size_t)m * H_ + h] = c_new;
            else if (g == 1) hid_out [(size_t)m * H_ + h] = h_new;
            else if (g == 2) hidB    [(size_t)m * H_ + h] = f2bf(h_new);
        }
      }
    }
}

// GEMM2: out = hidB @ WhyB^T + b
__global__ __launch_bounds__(256) void out_mm_bf16(
    const ushort* __restrict__ A, const ushort* __restrict__ Bm,
    const float* __restrict__ bw, float* __restrict__ out)
{
    __shared__ ushort As[128 * 32];
    __shared__ ushort Bs[128 * 32];
    const int tid  = threadIdx.x;
    const int lane = tid & 63;
    const int w    = tid >> 6;
    const int wm = w >> 1, wn = w & 1;
    const int blkN = blockIdx.x, blkM = blockIdx.y;
    const int srow = w * 16 + (lane >> 2);
    const int scol = (lane & 3) * 8;

    v4f acc[4][4];
    #pragma unroll
    for (int i = 0; i < 4; ++i)
      #pragma unroll
      for (int j = 0; j < 4; ++j) acc[i][j] = (v4f)0.f;

    for (int k0 = 0; k0 < H_; k0 += 32) {
        #pragma unroll
        for (int it = 0; it < 2; ++it) {
            const int row = it * 64 + srow;
            gload16(A  + (size_t)(blkM * 128 + row) * H_ + k0 + scol,
                    &As[w * 512 + it * 2048]);
            gload16(Bm + (size_t)(blkN * 128 + row) * H_ + k0 + scol,
                    &Bs[w * 512 + it * 2048]);
        }
        __syncthreads();
        v8s afr[4], bfr[4];
        #pragma unroll
        for (int i = 0; i < 4; ++i)
            afr[i] = *(const v8s*)&As[(wm * 64 + i * 16 + (lane & 15)) * 32 + (lane >> 4) * 8];
        #pragma unroll
        for (int j = 0; j < 4; ++j)
            bfr[j] = *(const v8s*)&Bs[(wn * 64 + j * 16 + (lane & 15)) * 32 + (lane >> 4) * 8];
        #pragma unroll
        for (int i = 0; i < 4; ++i)
          #pragma unroll
          for (int j = 0; j < 4; ++j)
            acc[i][j] = __builtin_amdgcn_mfma_f32_16x16x32_bf16(afr[i], bfr[j], acc[i][j], 0, 0, 0);
        __syncthreads();
    }
    #pragma unroll
    for (int i = 0; i < 4; ++i) {
      #pragma unroll
      for (int r = 0; r < 4; ++r) {
        const int m = blkM * 128 + wm * 64 + i * 16 + (lane >> 4) * 4 + r;
        #pragma unroll
        for (int j = 0; j < 4; ++j) {
            const int n = blkN * 128 + wn * 64 + j * 16 + (lane & 15);
            out[(size_t)m * O_ + n] = acc[i][j][r] + bw[n];
        }
      }
    }
}

// ------------------------------------------------ fallback (round-1, passing)
#define LDSTRIDE 48
__global__ __launch_bounds__(256) void lstm_gates_gemm(
    const float* __restrict__ x, const float* __restrict__ hs, const float* __restrict__ cs,
    const float* __restrict__ Wxi, const float* __restrict__ bxi, const float* __restrict__ Whi,
    const float* __restrict__ Wxf, const float* __restrict__ bxf, const float* __restrict__ Whf,
    const float* __restrict__ Wxc, const float* __restrict__ bxc, const float* __restrict__ Whc,
    const float* __restrict__ Wxo, const float* __restrict__ bxo, const float* __restrict__ Who,
    float* __restrict__ hid_out, float* __restrict__ cell_out)
{
    __shared__ ushort As[128 * LDSTRIDE];
    __shared__ ushort Bs[128 * LDSTRIDE];
    const int tid  = threadIdx.x;
    const int lane = tid & 63;
    const int wid  = tid >> 6;
    const int wm = wid >> 1, wn = wid & 1;
    const int blkN = blockIdx.x, blkM = blockIdx.y;
    const int r_s = tid >> 3;
    const int c_s = (tid & 7) * 4;
    v4f acc[4][4];
    #pragma unroll
    for (int i = 0; i < 4; ++i)
      #pragma unroll
      for (int j = 0; j < 4; ++j) acc[i][j] = (v4f)0.f;
    for (int k0 = 0; k0 < K1; k0 += 32) {
        const bool seg0 = (k0 < I_);
        #pragma unroll
        for (int it = 0; it < 4; ++it) {
            const int row = it * 32 + r_s;
            const int gm = blkM * 128 + row;
            const float* srcA = seg0 ? (x  + (size_t)gm * I_ + (k0 + c_s))
                                     : (hs + (size_t)gm * H_ + (k0 - I_ + c_s));
            float4 va = *(const float4*)srcA;
            *(ushort4*)&As[row * LDSTRIDE + c_s] =
                make_ushort4(f2bf(va.x), f2bf(va.y), f2bf(va.z), f2bf(va.w));
            const int n = blkN * 128 + row;
            const int hh = n >> 2, g = n & 3;
            const float* Wp;
            if (seg0) {
                const float* W = (g == 0) ? Wxi : (g == 1) ? Wxf : (g == 2) ? Wxc : Wxo;
                Wp = W + (size_t)hh * I_ + (k0 + c_s);
            } else {
                const float* W = (g == 0) ? Whi : (g == 1) ? Whf : (g == 2) ? Whc : Who;
                Wp = W + (size_t)hh * H_ + (k0 - I_ + c_s);
            }
            float4 vb = *(const float4*)Wp;
            *(ushort4*)&Bs[row * LDSTRIDE + c_s] =
                make_ushort4(f2bf(vb.x), f2bf(vb.y), f2bf(vb.z), f2bf(vb.w));
        }
        __syncthreads();
        v8s afr[4], bfr[4];
        #pragma unroll
        for (int i = 0; i < 4; ++i)
            afr[i] = *(const v8s*)&As[(wm * 64 + i * 16 + (lane & 15)) * LDSTRIDE + (lane >> 4) * 8];
        #pragma unroll
        for (int j = 0; j < 4; ++j)
            bfr[j] = *(const v8s*)&Bs[(wn * 64 + j * 16 + (lane & 15)) * LDSTRIDE + (lane >> 4) * 8];
        #pragma unroll
        for (int i = 0; i < 4; ++i)
          #pragma unroll
          for (int j = 0; j < 4; ++j)
            acc[i][j] = __builtin_amdgcn_mfma_f32_16x16x32_bf16(afr[i], bfr[j], acc[i][j], 0, 0, 0);
        __syncthreads();
    }
    const int g = lane & 3;
    int hj[4]; float biasj[4];
    #pragma unroll
    for (int j = 0; j < 4; ++j) {
        const int n = blkN * 128 + wn * 64 + j * 16 + (lane & 15);
        hj[j] = n >> 2;
        const float* bp = (g == 0) ? bxi : (g == 1) ? bxf : (g == 2) ? bxc : bxo;
        biasj[j] = bp[hj[j]];
    }
    #pragma unroll
    for (int i = 0; i < 4; ++i) {
      #pragma unroll
      for (int r = 0; r < 4; ++r) {
        const int m = blkM * 128 + wm * 64 + i * 16 + (lane >> 4) * 4 + r;
        #pragma unroll
        for (int j = 0; j < 4; ++j) {
            const float v = acc[i][j][r] + biasj[j];
            const int q = lane & 60;
            const float gi = __shfl(v, q + 0, 64);
            const float gf = __shfl(v, q + 1, 64);
            const float gc = __shfl(v, q + 2, 64);
            const float go = __shfl(v, q + 3, 64);
            const float Ig = sigm(gi), Fg = sigm(gf);
            const float Cg = tanh_f(gc), Og = sigm(go);
            const int h = hj[j];
            const float c_old = cs[(size_t)m * H_ + h];
            const float c_new = Fg * c_old + Ig * Cg;
            const float h_new = Og * tanh_f(c_new);
            if (g == 0)      cell_out[(size_t)m * H_ + h] = c_new;
            else if (g == 1) hid_out [(size_t)m * H_ + h] = h_new;
        }
      }
    }
}

__global__ __launch_bounds__(256) void out_gemm(
    const float* __restrict__ hid, const float* __restrict__ Why,
    const float* __restrict__ bw, float* __restrict__ out)
{
    __shared__ ushort As[128 * LDSTRIDE];
    __shared__ ushort Bs[128 * LDSTRIDE];
    const int tid  = threadIdx.x;
    const int lane = tid & 63;
    const int wid  = tid >> 6;
    const int wm = wid >> 1, wn = wid & 1;
    const int blkN = blockIdx.x, blkM = blockIdx.y;
    const int r_s = tid >> 3;
    const int c_s = (tid & 7) * 4;
    v4f acc[4][4];
    #pragma unroll
    for (int i = 0; i < 4; ++i)
      #pragma unroll
      for (int j = 0; j < 4; ++j) acc[i][j] = (v4f)0.f;
    for (int k0 = 0; k0 < H_; k0 += 32) {
        #pragma unroll
        for (int it = 0; it < 4; ++it) {
            const int row = it * 32 + r_s;
            const int gm = blkM * 128 + row;
            float4 va = *(const float4*)(hid + (size_t)gm * H_ + (k0 + c_s));
            *(ushort4*)&As[row * LDSTRIDE + c_s] =
                make_ushort4(f2bf(va.x), f2bf(va.y), f2bf(va.z), f2bf(va.w));
            const int n = blkN * 128 + row;
            float4 vb = *(const float4*)(Why + (size_t)n * H_ + (k0 + c_s));
            *(ushort4*)&Bs[row * LDSTRIDE + c_s] =
                make_ushort4(f2bf(vb.x), f2bf(vb.y), f2bf(vb.z), f2bf(vb.w));
        }
        __syncthreads();
        v8s afr[4], bfr[4];
        #pragma unroll
        for (int i = 0; i < 4; ++i)
            afr[i] = *(const v8s*)&As[(wm * 64 + i * 16 + (lane & 15)) * LDSTRIDE + (lane >> 4) * 8];
        #pragma unroll
        for (int j = 0; j < 4; ++j)
            bfr[j] = *(const v8s*)&Bs[(wn * 64 + j * 16 + (lane & 15)) * LDSTRIDE + (lane >> 4) * 8];
        #pragma unroll
        for (int i = 0; i < 4; ++i)
          #pragma unroll
          for (int j = 0; j < 4; ++j)
            acc[i][j] = __builtin_amdgcn_mfma_f32_16x16x32_bf16(afr[i], bfr[j], acc[i][j], 0, 0, 0);
        __syncthreads();
    }
    #pragma unroll
    for (int i = 0; i < 4; ++i) {
      #pragma unroll
      for (int r = 0; r < 4; ++r) {
        const int m = blkM * 128 + wm * 64 + i * 16 + (lane >> 4) * 4 + r;
        #pragma unroll
        for (int j = 0; j < 4; ++j) {
            const int n = blkN * 128 + wn * 64 + j * 16 + (lane & 15);
            out[(size_t)m * O_ + n] = acc[i][j][r] + bw[n];
        }
      }
    }
}

extern "C" void kernel_launch(void* const* d_in, const int* in_sizes, int n_in,
                              void* d_out, int out_size, void* d_ws, size_t ws_size,
                              hipStream_t stream) {
    const float* x   = (const float*)d_in[0];
    const float* hs  = (const float*)d_in[1];
    const float* cs  = (const float*)d_in[2];
    const float* Wxi = (const float*)d_in[3];
    const float* bxi = (const float*)d_in[4];
    const float* Whi = (const float*)d_in[5];
    const float* Wxf = (const float*)d_in[6];
    const float* bxf = (const float*)d_in[7];
    const float* Whf = (const float*)d_in[8];
    const float* Wxc = (const float*)d_in[9];
    const float* bxc = (const float*)d_in[10];
    const float* Whc = (const float*)d_in[11];
    const float* Wxo = (const float*)d_in[12];
    const float* bxo = (const float*)d_in[13];
    const float* Who = (const float*)d_in[14];
    const float* Why = (const float*)d_in[15];
    const float* bwy = (const float*)d_in[16];

    float* out      = (float*)d_out;
    float* hid_out  = out + (size_t)B_ * O_;
    float* cell_out = hid_out + (size_t)B_ * H_;

    // workspace layout (bf16)
    const size_t szW = (size_t)N1 * K1;          // 8192*3072
    const size_t szX = (size_t)B_ * K1;          // 4096*3072
    const size_t szY = (size_t)O_ * H_;          // 1024*2048
    const size_t szH = (size_t)B_ * H_;          // 4096*2048
    const size_t need = (szW + szX + szY + szH) * sizeof(ushort);

    if (ws_size >= need) {
        ushort* Wcat = (ushort*)d_ws;
        ushort* Xcat = Wcat + szW;
        ushort* WhyB = Xcat + szX;
        ushort* HidB = WhyB + szY;

        convert_w<<<dim3(N1), 384, 0, stream>>>(Wxi, Whi, Wxf, Whf, Wxc, Whc, Wxo, Who, Wcat);
        convert_x<<<dim3(B_), 384, 0, stream>>>(x, hs, Xcat);
        convert_y<<<dim3(O_), 256, 0, stream>>>(Why, WhyB);

        gates_mm_bf16<<<dim3(N1 / 128, B_ / 128), 256, 0, stream>>>(
            Xcat, Wcat, cs, bxi, bxf, bxc, bxo, hid_out, cell_out, HidB);
        out_mm_bf16<<<dim3(O_ / 128, B_ / 128), 256, 0, stream>>>(
            HidB, WhyB, bwy, out);
    } else {
        lstm_gates_gemm<<<dim3(N1 / 128, B_ / 128), 256, 0, stream>>>(
            x, hs, cs, Wxi, bxi, Whi, Wxf, bxf, Whf, Wxc, bxc, Whc, Wxo, bxo, Who,
            hid_out, cell_out);
        out_gemm<<<dim3(O_ / 128, B_ / 128), 256, 0, stream>>>(hid_out, Why, bwy, out);
    }
}